// Round 6
// baseline (222.781 us; speedup 1.0000x reference)
//
#include <hip/hip_runtime.h>

#define S 1048576
typedef unsigned short u16;
typedef unsigned int u32;
typedef __attribute__((ext_vector_type(8))) short s8v;   // 8 bf16 (4 VGPRs)
typedef __attribute__((ext_vector_type(4))) float f4v;   // MFMA acc

__device__ __forceinline__ float bf2f(u16 u){
    union { float f; u32 u; } v; v.u = ((u32)u) << 16; return v.f;
}
__device__ __forceinline__ u16 f2bf(float x){
    u32 u = __float_as_uint(x);
    u32 r = (u + 0x7FFFu + ((u >> 16) & 1u)) >> 16;   // RNE
    return (u16)r;
}
__device__ __forceinline__ void splitf(float x, u16& h, u16& l){
    h = f2bf(x);
    l = f2bf(x - bf2f(h));
}
__device__ __forceinline__ float pairf(const u16* H, const u16* L, size_t off){
    return bf2f(H[off]) + bf2f(L[off]);
}
// XOR-swizzled LDS index (u16 units): 128-byte rows of 8 16B chunks, chunk ^= row&7
__device__ __forceinline__ int sidx(int r, int c){ return (r<<6) + (((c) ^ (r&7))<<3); }
// async global->LDS, 16B per lane; LDS dest = wave-uniform base + lane*16
__device__ __forceinline__ void gl16(const void* g, void* l){
    __builtin_amdgcn_global_load_lds((const __attribute__((address_space(1))) void*)g,
                                     (__attribute__((address_space(3))) void*)l, 16, 0, 0);
}

// A_z = 0.5*(G_z - G_z^T) split pair (64x64 tiles, z=bid>>8). 768 blocks.
__global__ __launch_bounds__(256) void pre_k(const float* __restrict__ G, u16* __restrict__ Abase){
    __shared__ float Gt[64][65];
    const int bid = blockIdx.x;
    const int t = threadIdx.x;
    const int bx = bid & 15, by = (bid >> 4) & 15, z = bid >> 8;
    const float* Gz = G + (size_t)z*S;
    u16* Ah = Abase + (size_t)z*2*S;
    u16* Al = Ah + S;
    const int row = t >> 2, cq = (t & 3) << 4;
    const int r0 = by << 6, c0 = bx << 6;
    #pragma unroll
    for (int g = 0; g < 4; ++g){
        float4 v = *(const float4*)(Gz + (size_t)(c0+row)*1024 + r0 + cq + g*4);
        Gt[row][cq+g*4+0]=v.x; Gt[row][cq+g*4+1]=v.y; Gt[row][cq+g*4+2]=v.z; Gt[row][cq+g*4+3]=v.w;
    }
    __syncthreads();
    #pragma unroll
    for (int g = 0; g < 2; ++g){
        const float* p = Gz + (size_t)(r0+row)*1024 + c0 + cq + g*8;
        float4 v0 = *(const float4*)(p);
        float4 v1 = *(const float4*)(p+4);
        float xs[8] = {v0.x,v0.y,v0.z,v0.w,v1.x,v1.y,v1.z,v1.w};
        s8v sh, sl;
        #pragma unroll
        for (int i = 0; i < 8; ++i){
            float gt = Gt[cq + g*8 + i][row];
            u16 h,l; splitf(0.5f*(xs[i]-gt), h, l);
            sh[i] = (short)h; sl[i] = (short)l;
        }
        *(s8v*)(Ah + (size_t)(r0+row)*1024 + c0 + cq + g*8) = sh;
        *(s8v*)(Al + (size_t)(r0+row)*1024 + c0 + cq + g*8) = sl;
    }
}

// acc = A * Bt^T with split-bf16 MFMA (3 passes), DMA staging, dbuf, 1 barrier/K-step.
// Skew identities (no negation): A*A^T = -A^2 ; (-A^2)*A^T = A^3.
// MODE 0: C pair = acc.
// MODE 1: C pair = acc AND O2 = (1/6)I + (1/24)*Bt - (1/120)*Aop + (1/720)*acc   (O2 = Mb)
// MODE 2: O2 only = I + Pa - 0.5*Pa2 - acc  (O2 = E); z==2 also writes E2^T pair to E2t.
// XFUSE: blocks with blockIdx.x >= 16 convert X fp32 -> bf16 hi (grid-stride).
template<int MODE, bool XFUSE>
__global__ __launch_bounds__(256) void gemm64_k(const u16* __restrict__ Abase, const u16* __restrict__ Btbase,
                                                u16* __restrict__ Cbase,
                                                const u16* __restrict__ Pab, const u16* __restrict__ Pa2b,
                                                u16* __restrict__ O2base, u16* __restrict__ E2t,
                                                const float* __restrict__ X, u16* __restrict__ Xh){
    __shared__ u16 lds[2][16384];   // per buf: Ah 0, Al 4096, Bh 8192, Bl 12288 (64x64 u16 each)
    const int t = threadIdx.x;
    if (XFUSE && blockIdx.x >= 16){
        const int e = ((int)(blockIdx.z*gridDim.y + blockIdx.y))*((int)gridDim.x - 16) + ((int)blockIdx.x - 16);
        const int E = (int)(gridDim.x - 16)*(int)gridDim.y*(int)gridDim.z;
        for (int u = e; u < 8192; u += E){
            const size_t idx8 = (size_t)u*2048 + (size_t)t*8;
            float4 v0 = *(const float4*)(X+idx8);
            float4 v1 = *(const float4*)(X+idx8+4);
            float xs[8] = {v0.x,v0.y,v0.z,v0.w,v1.x,v1.y,v1.z,v1.w};
            s8v h;
            #pragma unroll
            for (int i = 0; i < 8; ++i) h[i] = (short)f2bf(xs[i]);
            *(s8v*)(Xh+idx8) = h;
        }
        return;
    }
    const int z = blockIdx.z;
    const u16* Ah = Abase  + (size_t)z*2*S; const u16* Al = Ah + S;
    const u16* Bh = Btbase + (size_t)z*2*S; const u16* Bl = Bh + S;
    u16* Ch = Cbase + (size_t)z*2*S;        u16* Cl = Ch + S;
    const u16* Pah = Pab + (size_t)z*2*S;   const u16* Pal = Pah + S;
    const u16* P2h = Pa2b + (size_t)z*2*S;  const u16* P2l = P2h + S;
    u16* O2h = O2base + (size_t)z*2*S;      u16* O2l = O2h + S;
    const int brow = blockIdx.y << 6, bcol = blockIdx.x << 6;
    const int lane = t & 63, w = t >> 6;
    const int wm = (w >> 1) << 5, wn = (w & 1) << 5;
    const int lr = lane & 15, g = lane >> 4;
    int qq[2]; size_t goA[2], goB[2];
    #pragma unroll
    for (int i = 0; i < 2; ++i){
        int q = (((w<<1)+i)<<6) + lane;
        int r = q >> 3, c = lane & 7;
        qq[i] = q << 3;
        goA[i] = (size_t)(brow+r)*1024 + ((c^(r&7))<<3);
        goB[i] = (size_t)(bcol+r)*1024 + ((c^(r&7))<<3);
    }
    f4v acc[2][2] = {};
    {
        u16* L = lds[0];
        #pragma unroll
        for (int i = 0; i < 2; ++i){
            gl16(Ah + goA[i], L + qq[i]);
            gl16(Al + goA[i], L + 4096 + qq[i]);
            gl16(Bh + goB[i], L + 8192 + qq[i]);
            gl16(Bl + goB[i], L + 12288 + qq[i]);
        }
    }
    int cur = 0;
    for (int kt = 0; kt < 16; ++kt){
        __syncthreads();
        if (kt < 15){
            u16* L = lds[cur^1];
            const int k0 = (kt+1) << 6;
            #pragma unroll
            for (int i = 0; i < 2; ++i){
                gl16(Ah + goA[i] + k0, L + qq[i]);
                gl16(Al + goA[i] + k0, L + 4096 + qq[i]);
                gl16(Bh + goB[i] + k0, L + 8192 + qq[i]);
                gl16(Bl + goB[i] + k0, L + 12288 + qq[i]);
            }
        }
        const u16* L = lds[cur];
        #pragma unroll
        for (int ks = 0; ks < 2; ++ks){
            const int ch = (ks << 2) + g;
            s8v a_h[2], a_l[2], b_h[2], b_l[2];
            #pragma unroll
            for (int f = 0; f < 2; ++f){
                const int ra = wm+(f<<4)+lr, rb = wn+(f<<4)+lr;
                a_h[f] = *(const s8v*)&L[sidx(ra,ch)];
                a_l[f] = *(const s8v*)&L[4096 + sidx(ra,ch)];
                b_h[f] = *(const s8v*)&L[8192 + sidx(rb,ch)];
                b_l[f] = *(const s8v*)&L[12288 + sidx(rb,ch)];
            }
            __builtin_amdgcn_s_setprio(1);
            #pragma unroll
            for (int mf = 0; mf < 2; ++mf)
                #pragma unroll
                for (int nf = 0; nf < 2; ++nf){
                    acc[mf][nf] = __builtin_amdgcn_mfma_f32_16x16x32_bf16(a_h[mf], b_h[nf], acc[mf][nf], 0,0,0);
                    acc[mf][nf] = __builtin_amdgcn_mfma_f32_16x16x32_bf16(a_l[mf], b_h[nf], acc[mf][nf], 0,0,0);
                    acc[mf][nf] = __builtin_amdgcn_mfma_f32_16x16x32_bf16(a_h[mf], b_l[nf], acc[mf][nf], 0,0,0);
                }
            __builtin_amdgcn_s_setprio(0);
        }
        cur ^= 1;
    }
    const int orr = g << 2;
    #pragma unroll
    for (int mf = 0; mf < 2; ++mf)
        #pragma unroll
        for (int nf = 0; nf < 2; ++nf)
            #pragma unroll
            for (int r = 0; r < 4; ++r){
                const int orow = brow + wm + (mf<<4) + orr + r;
                const int ocol = bcol + wn + (nf<<4) + lr;
                const size_t off = (size_t)orow*1024 + ocol;
                const float av = acc[mf][nf][r];
                if (MODE == 0 || MODE == 1){
                    u16 h,l; splitf(av, h, l);
                    Ch[off] = h; Cl[off] = l;
                }
                if (MODE == 1){
                    float a  = pairf(Bh, Bl, off);      // A
                    float a2 = pairf(Ah, Al, off);      // -A^2
                    float mb = (1.0f/24.0f)*a - (1.0f/120.0f)*a2 + (1.0f/720.0f)*av
                             + (orow == ocol ? (1.0f/6.0f) : 0.0f);
                    u16 h,l; splitf(mb, h, l);
                    O2h[off] = h; O2l[off] = l;
                }
                if (MODE == 2){
                    float a  = pairf(Pah, Pal, off);    // A
                    float a2 = pairf(P2h, P2l, off);    // -A^2
                    float e = a - 0.5f*a2 - av + (orow == ocol ? 1.0f : 0.0f);
                    u16 h,l; splitf(e, h, l);
                    O2h[off] = h; O2l[off] = l;
                    if (z == 2){                        // also write E2^T
                        const size_t offT = (size_t)ocol*1024 + orow;
                        E2t[offT] = h; E2t[S + offT] = l;
                    }
                }
            }
}

// C = A * Bt^T, 32x32 tile, 4 waves (1 frag each), DMA staging, dbuf. For small z=1 GEMMs.
__global__ __launch_bounds__(256) void gemm32_k(const u16* __restrict__ Ah, const u16* __restrict__ Bh,
                                                u16* __restrict__ Ch){
    __shared__ u16 lds[2][8192];   // per buf: Ah 0, Al 2048, Bh 4096, Bl 6144 (32x64 u16 each)
    const u16* Al = Ah + S; const u16* Bl = Bh + S;
    u16* Cl = Ch + S;
    const int t = threadIdx.x;
    const int brow = blockIdx.y << 5, bcol = blockIdx.x << 5;
    const int lane = t & 63, w = t >> 6;
    const int wm = (w >> 1) << 4, wn = (w & 1) << 4;
    const int lr = lane & 15, g = lane >> 4;
    // staging: wave w owns region w (0:Ah 1:Al 2:Bh 3:Bl); 256 chunks/region, 4 issues/lane
    const u16* gsrc = (w == 0) ? Ah : (w == 1) ? Al : (w == 2) ? Bh : Bl;
    const int rbase = (w < 2) ? brow : bcol;
    const int lreg = w << 11;
    int qq[4]; size_t go[4];
    #pragma unroll
    for (int i = 0; i < 4; ++i){
        int q = (i<<6) + lane;
        int r = q >> 3, c = lane & 7;
        qq[i] = lreg + (q << 3);
        go[i] = (size_t)(rbase+r)*1024 + ((c^(r&7))<<3);
    }
    f4v acc = {};
    {
        u16* L = lds[0];
        #pragma unroll
        for (int i = 0; i < 4; ++i) gl16(gsrc + go[i], L + qq[i]);
    }
    int cur = 0;
    for (int kt = 0; kt < 16; ++kt){
        __syncthreads();
        if (kt < 15){
            u16* L = lds[cur^1];
            const int k0 = (kt+1) << 6;
            #pragma unroll
            for (int i = 0; i < 4; ++i) gl16(gsrc + go[i] + k0, L + qq[i]);
        }
        const u16* L = lds[cur];
        #pragma unroll
        for (int ks = 0; ks < 2; ++ks){
            const int ch = (ks << 2) + g;
            const int ra = wm + lr, rb = wn + lr;
            s8v a_h = *(const s8v*)&L[sidx(ra,ch)];
            s8v a_l = *(const s8v*)&L[2048 + sidx(ra,ch)];
            s8v b_h = *(const s8v*)&L[4096 + sidx(rb,ch)];
            s8v b_l = *(const s8v*)&L[6144 + sidx(rb,ch)];
            acc = __builtin_amdgcn_mfma_f32_16x16x32_bf16(a_h, b_h, acc, 0,0,0);
            acc = __builtin_amdgcn_mfma_f32_16x16x32_bf16(a_l, b_h, acc, 0,0,0);
            acc = __builtin_amdgcn_mfma_f32_16x16x32_bf16(a_h, b_l, acc, 0,0,0);
        }
        cur ^= 1;
    }
    const int orr = g << 2;
    #pragma unroll
    for (int r = 0; r < 4; ++r){
        const int orow = brow + wm + orr + r;
        const int ocol = bcol + wn + lr;
        const size_t off = (size_t)orow*1024 + ocol;
        u16 h,l; splitf(acc[r], h, l);
        Ch[off] = h; Cl[off] = l;
    }
}

// Y[16384,1024] = X * R.  256x128x64 tile, 8 waves, DMA staging, dbuf, 1 barrier/K-step.
__global__ __launch_bounds__(512) void gemm_big2(const u16* __restrict__ Xh, const u16* __restrict__ Rth,
                                                 float* __restrict__ Y){
    __shared__ u16 lds[2][32768];  // per buf: X 0..16383 (256x64), Bh 16384.. (128x64), Bl 24576..
    const u16* Rtl = Rth + S;
    const int bid = blockIdx.x;
    const int swz = (bid & 7)*64 + (bid >> 3);     // chunked XCD swizzle (512 blocks, bijective)
    const int by = swz >> 3, bx = swz & 7;
    const int brow = by << 8, bcol = bx << 7;
    const int t = threadIdx.x;
    const int lane = t & 63, w = t >> 6;
    const int wm = (w >> 2) << 7, wn = (w & 3) << 5;   // wave tile 128x32
    const int lr = lane & 15, g = lane >> 4;
    int xq[4]; size_t gx[4];
    #pragma unroll
    for (int i = 0; i < 4; ++i){
        int q = (((w<<2)+i)<<6) + lane;
        int r = q >> 3, c = lane & 7;
        xq[i] = q << 3;
        gx[i] = (size_t)(brow+r)*1024 + ((c^(r&7))<<3);
    }
    int bq[2]; size_t gb[2];
    #pragma unroll
    for (int i = 0; i < 2; ++i){
        int q = (((w<<1)+i)<<6) + lane;
        int r = q >> 3, c = lane & 7;
        bq[i] = q << 3;
        gb[i] = (size_t)(bcol+r)*1024 + ((c^(r&7))<<3);
    }
    f4v acc[8][2] = {};
    {
        u16* L = lds[0];
        #pragma unroll
        for (int i = 0; i < 4; ++i) gl16(Xh + gx[i], L + xq[i]);
        #pragma unroll
        for (int i = 0; i < 2; ++i){
            gl16(Rth + gb[i], L + 16384 + bq[i]);
            gl16(Rtl + gb[i], L + 24576 + bq[i]);
        }
    }
    int cur = 0;
    for (int kt = 0; kt < 16; ++kt){
        __syncthreads();
        if (kt < 15){
            u16* L = lds[cur^1];
            const int k0 = (kt+1) << 6;
            #pragma unroll
            for (int i = 0; i < 4; ++i) gl16(Xh + gx[i] + k0, L + xq[i]);
            #pragma unroll
            for (int i = 0; i < 2; ++i){
                gl16(Rth + gb[i] + k0, L + 16384 + bq[i]);
                gl16(Rtl + gb[i] + k0, L + 24576 + bq[i]);
            }
        }
        const u16* L = lds[cur];
        #pragma unroll
        for (int ks = 0; ks < 2; ++ks){
            const int ch = (ks << 2) + g;
            s8v bh[2], bl[2];
            #pragma unroll
            for (int nf = 0; nf < 2; ++nf){
                const int rb = wn+(nf<<4)+lr;
                bh[nf] = *(const s8v*)&L[16384 + sidx(rb,ch)];
                bl[nf] = *(const s8v*)&L[24576 + sidx(rb,ch)];
            }
            __builtin_amdgcn_s_setprio(1);
            #pragma unroll
            for (int mf = 0; mf < 8; ++mf){
                const int ra = wm+(mf<<4)+lr;
                s8v a = *(const s8v*)&L[sidx(ra,ch)];
                #pragma unroll
                for (int nf = 0; nf < 2; ++nf){
                    acc[mf][nf] = __builtin_amdgcn_mfma_f32_16x16x32_bf16(a, bh[nf], acc[mf][nf], 0,0,0);
                    acc[mf][nf] = __builtin_amdgcn_mfma_f32_16x16x32_bf16(a, bl[nf], acc[mf][nf], 0,0,0);
                }
            }
            __builtin_amdgcn_s_setprio(0);
        }
        cur ^= 1;
    }
    const int orr = g << 2;
    #pragma unroll
    for (int mf = 0; mf < 8; ++mf)
        #pragma unroll
        for (int nf = 0; nf < 2; ++nf)
            #pragma unroll
            for (int r = 0; r < 4; ++r){
                int orow = brow + wm + (mf<<4) + orr + r;
                int ocol = bcol + wn + (nf<<4) + lr;
                Y[(size_t)orow*1024 + ocol] = acc[mf][nf][r];
            }
}

// Fallback (no workspace): reg-staged 128x128, X converted on the fly.
__global__ __launch_bounds__(256) void gemm_big_f(const float* __restrict__ Xv, const u16* __restrict__ Rth,
                                                  float* __restrict__ Y){
    __shared__ u16 Xs[128*64], Bhs[128*64], Bls[128*64];
    const u16* Rtl = Rth + S;
    const int bid = blockIdx.x;
    const int swz = (bid & 7)*128 + (bid >> 3);
    const int bx = swz & 7, by = swz >> 3;
    const int brow = by << 7, bcol = bx << 7;
    const int t = threadIdx.x;
    const int sr = t >> 1, cb = (t & 1) << 2;
    const int lane = t & 63, w = t >> 6;
    const int wm = (w >> 1) << 6, wn = (w & 1) << 6;
    const int lr = lane & 15, g = lane >> 4;
    s8v xr[4], bhr[4], blr[4];
    auto load_tile = [&](int k0){
        #pragma unroll
        for (int i = 0; i < 4; ++i){
            const size_t bo = (size_t)(bcol+sr)*1024 + k0 + ((cb+i)<<3);
            bhr[i] = *(const s8v*)(Rth + bo);
            blr[i] = *(const s8v*)(Rtl + bo);
        }
        #pragma unroll
        for (int i = 0; i < 4; ++i){
            const float* p = Xv + (size_t)(brow+sr)*1024 + k0 + ((cb+i)<<3);
            float4 f0 = *(const float4*)(p), f1 = *(const float4*)(p+4);
            float xs[8] = {f0.x,f0.y,f0.z,f0.w,f1.x,f1.y,f1.z,f1.w};
            #pragma unroll
            for (int j = 0; j < 8; ++j) xr[i][j] = (short)f2bf(xs[j]);
        }
    };
    load_tile(0);
    f4v acc[4][4] = {};
    for (int k0 = 0; k0 < 1024; k0 += 64){
        __syncthreads();
        #pragma unroll
        for (int i = 0; i < 4; ++i){
            const int si = sidx(sr, cb+i);
            *(s8v*)&Xs[si]  = xr[i];
            *(s8v*)&Bhs[si] = bhr[i];
            *(s8v*)&Bls[si] = blr[i];
        }
        __syncthreads();
        if (k0 < 960) load_tile(k0 + 64);
        #pragma unroll
        for (int ks = 0; ks < 2; ++ks){
            const int ch = (ks << 2) + g;
            s8v bhf[4], blf[4];
            #pragma unroll
            for (int nf = 0; nf < 4; ++nf){
                bhf[nf] = *(const s8v*)&Bhs[sidx(wn+(nf<<4)+lr, ch)];
                blf[nf] = *(const s8v*)&Bls[sidx(wn+(nf<<4)+lr, ch)];
            }
            #pragma unroll
            for (int mf = 0; mf < 4; ++mf){
                s8v ah = *(const s8v*)&Xs[sidx(wm+(mf<<4)+lr, ch)];
                #pragma unroll
                for (int nf = 0; nf < 4; ++nf){
                    acc[mf][nf] = __builtin_amdgcn_mfma_f32_16x16x32_bf16(ah, bhf[nf], acc[mf][nf], 0,0,0);
                    acc[mf][nf] = __builtin_amdgcn_mfma_f32_16x16x32_bf16(ah, blf[nf], acc[mf][nf], 0,0,0);
                }
            }
        }
    }
    const int orr = g << 2;
    #pragma unroll
    for (int mf = 0; mf < 4; ++mf)
        #pragma unroll
        for (int nf = 0; nf < 4; ++nf)
            #pragma unroll
            for (int r = 0; r < 4; ++r){
                int orow = brow + wm + (mf<<4) + orr + r;
                int ocol = bcol + wn + (nf<<4) + lr;
                Y[(size_t)orow*1024 + ocol] = acc[mf][nf][r];
            }
}

extern "C" void kernel_launch(void* const* d_in, const int* in_sizes, int n_in,
                              void* d_out, int out_size, void* d_ws, size_t ws_size,
                              hipStream_t stream) {
    const float* X = (const float*)d_in[0];   // [16384,1024] fp32
    const float* G = (const float*)d_in[1];   // [3,1024,1024] fp32
    float* out = (float*)d_out;
    u16* ob = (u16*)d_out;                    // 16 pair-slots of 2*S u16 each
    auto slot = [&](int i){ return ob + (size_t)i*2*S; };
    u16* RT = (u16*)d_ws;                     // R^T split pair (4 MB)
    u16* Xh = RT + (size_t)2*S;               // X hi bf16 (32 MB)
    const bool ws_ok = ws_size >= (size_t)36*S; // bytes: 2S*2 (RT) + 16S*2 (Xh)

    dim3 b(256);
    // slots: A:0-2  A2':3-5  A3:6-8  Mb:9-11  E:12-14  E2t:15  M1:0
    pre_k<<<dim3(768), b, 0, stream>>>(G, slot(0));                                   // A pair
    if (ws_ok)
        gemm64_k<0,true><<<dim3(48,16,3), b, 0, stream>>>(slot(0), slot(0), slot(3),
                                                          slot(0), slot(0), slot(3), slot(15),
                                                          X, Xh);                     // A2' = -A^2 (+X conv)
    else
        gemm64_k<0,false><<<dim3(16,16,3), b, 0, stream>>>(slot(0), slot(0), slot(3),
                                                           slot(0), slot(0), slot(3), slot(15),
                                                           X, Xh);
    gemm64_k<1,false><<<dim3(16,16,3), b, 0, stream>>>(slot(3), slot(0), slot(6),
                                                       slot(0), slot(3), slot(9), slot(15),
                                                       X, Xh);                        // A3 ; Mb
    gemm64_k<2,false><<<dim3(16,16,3), b, 0, stream>>>(slot(9), slot(6), slot(9),
                                                       slot(0), slot(3), slot(12), slot(15),
                                                       X, Xh);                        // E (+E2^T for z=2)
    gemm32_k<<<dim3(32,32), b, 0, stream>>>(slot(15), slot(13), slot(0));             // M1 = E2^T*E1^T
    gemm32_k<<<dim3(32,32), b, 0, stream>>>(slot(0), slot(12), RT);                   // RT = M1*E0^T
    if (ws_ok)
        gemm_big2<<<dim3(512), dim3(512), 0, stream>>>(Xh, RT, out);
    else
        gemm_big_f<<<dim3(1024), b, 0, stream>>>(X, RT, out);
}

// Round 7
// 147.346 us; speedup vs baseline: 1.5120x; 1.5120x over previous
//
#include <hip/hip_runtime.h>

#define S 1048576
typedef unsigned short u16;
typedef unsigned int u32;
typedef __attribute__((ext_vector_type(8))) short s8v;   // 8 bf16 (4 VGPRs)
typedef __attribute__((ext_vector_type(4))) float f4v;   // MFMA acc

__device__ __forceinline__ float bf2f(u16 u){
    union { float f; u32 u; } v; v.u = ((u32)u) << 16; return v.f;
}
__device__ __forceinline__ u16 f2bf(float x){
    u32 u = __float_as_uint(x);
    u32 r = (u + 0x7FFFu + ((u >> 16) & 1u)) >> 16;   // RNE
    return (u16)r;
}
__device__ __forceinline__ void splitf(float x, u16& h, u16& l){
    h = f2bf(x);
    l = f2bf(x - bf2f(h));
}
__device__ __forceinline__ float pairf(const u16* H, const u16* L, size_t off){
    return bf2f(H[off]) + bf2f(L[off]);
}
// XOR-swizzled LDS index (u16 units): 128-byte rows of 8 16B chunks, chunk ^= row&7
__device__ __forceinline__ int sidx(int r, int c){ return (r<<6) + (((c) ^ (r&7))<<3); }
// async global->LDS, 16B per lane; LDS dest = wave-uniform base + lane*16
__device__ __forceinline__ void gl16(const void* g, void* l){
    __builtin_amdgcn_global_load_lds((const __attribute__((address_space(1))) void*)g,
                                     (__attribute__((address_space(3))) void*)l, 16, 0, 0);
}

// A_z = 0.5*(G_z - G_z^T) split pair (64x64 tiles, z=bid>>8). 768 blocks.
__global__ __launch_bounds__(256) void pre_k(const float* __restrict__ G, u16* __restrict__ Abase){
    __shared__ float Gt[64][65];
    const int bid = blockIdx.x;
    const int t = threadIdx.x;
    const int bx = bid & 15, by = (bid >> 4) & 15, z = bid >> 8;
    const float* Gz = G + (size_t)z*S;
    u16* Ah = Abase + (size_t)z*2*S;
    u16* Al = Ah + S;
    const int row = t >> 2, cq = (t & 3) << 4;
    const int r0 = by << 6, c0 = bx << 6;
    #pragma unroll
    for (int g = 0; g < 4; ++g){
        float4 v = *(const float4*)(Gz + (size_t)(c0+row)*1024 + r0 + cq + g*4);
        Gt[row][cq+g*4+0]=v.x; Gt[row][cq+g*4+1]=v.y; Gt[row][cq+g*4+2]=v.z; Gt[row][cq+g*4+3]=v.w;
    }
    __syncthreads();
    #pragma unroll
    for (int g = 0; g < 2; ++g){
        const float* p = Gz + (size_t)(r0+row)*1024 + c0 + cq + g*8;
        float4 v0 = *(const float4*)(p);
        float4 v1 = *(const float4*)(p+4);
        float xs[8] = {v0.x,v0.y,v0.z,v0.w,v1.x,v1.y,v1.z,v1.w};
        s8v sh, sl;
        #pragma unroll
        for (int i = 0; i < 8; ++i){
            float gt = Gt[cq + g*8 + i][row];
            u16 h,l; splitf(0.5f*(xs[i]-gt), h, l);
            sh[i] = (short)h; sl[i] = (short)l;
        }
        *(s8v*)(Ah + (size_t)(r0+row)*1024 + c0 + cq + g*8) = sh;
        *(s8v*)(Al + (size_t)(r0+row)*1024 + c0 + cq + g*8) = sl;
    }
}

// acc = Ah * Bth^T, single-pass bf16 MFMA (hi planes only), DMA staging, dbuf, 1 barrier/K-step.
// Skew identities: A*A^T = -A^2 ; (-A^2)*A^T = A^3.  Chain precision analysis: 1-pass rel err
// ~2^-8 on A2/A3 propagates <1e-3 into y (threshold 0.114) — lo-plane passes unnecessary here.
// MODE 0: C pair = acc.
// MODE 1: C pair = acc AND O2 = (1/6)I + (1/24)*Bt - (1/120)*Aop + (1/720)*acc   (O2 = Mb)
// MODE 2: O2 only = I + Pa - 0.5*Pa2 - acc  (O2 = E); z==2 also writes E2^T pair to E2t.
// XFUSE: blocks with blockIdx.x >= 16 convert X fp32 -> bf16 hi (grid-stride).
template<int MODE, bool XFUSE>
__global__ __launch_bounds__(256) void gemm64_k(const u16* __restrict__ Abase, const u16* __restrict__ Btbase,
                                                u16* __restrict__ Cbase,
                                                const u16* __restrict__ Pab, const u16* __restrict__ Pa2b,
                                                u16* __restrict__ O2base, u16* __restrict__ E2t,
                                                const float* __restrict__ X, u16* __restrict__ Xh){
    __shared__ u16 lds[2][8192];   // per buf: Ah 0..4095, Bh 4096..8191 (64x64 u16 each)
    const int t = threadIdx.x;
    if (XFUSE && blockIdx.x >= 16){
        const int e = ((int)(blockIdx.z*gridDim.y + blockIdx.y))*((int)gridDim.x - 16) + ((int)blockIdx.x - 16);
        const int E = (int)(gridDim.x - 16)*(int)gridDim.y*(int)gridDim.z;
        for (int u = e; u < 8192; u += E){
            const size_t idx8 = (size_t)u*2048 + (size_t)t*8;
            float4 v0 = *(const float4*)(X+idx8);
            float4 v1 = *(const float4*)(X+idx8+4);
            float xs[8] = {v0.x,v0.y,v0.z,v0.w,v1.x,v1.y,v1.z,v1.w};
            s8v h;
            #pragma unroll
            for (int i = 0; i < 8; ++i) h[i] = (short)f2bf(xs[i]);
            *(s8v*)(Xh+idx8) = h;
        }
        return;
    }
    const int z = blockIdx.z;
    const u16* Ah = Abase  + (size_t)z*2*S; const u16* Al = Ah + S;
    const u16* Bh = Btbase + (size_t)z*2*S; const u16* Bl = Bh + S;
    u16* Ch = Cbase + (size_t)z*2*S;        u16* Cl = Ch + S;
    const u16* Pah = Pab + (size_t)z*2*S;   const u16* Pal = Pah + S;
    const u16* P2h = Pa2b + (size_t)z*2*S;  const u16* P2l = P2h + S;
    u16* O2h = O2base + (size_t)z*2*S;      u16* O2l = O2h + S;
    const int brow = blockIdx.y << 6, bcol = blockIdx.x << 6;
    const int lane = t & 63, w = t >> 6;
    const int wm = (w >> 1) << 5, wn = (w & 1) << 5;
    const int lr = lane & 15, g = lane >> 4;
    int qq[2]; size_t goA[2], goB[2];
    #pragma unroll
    for (int i = 0; i < 2; ++i){
        int q = (((w<<1)+i)<<6) + lane;
        int r = q >> 3, c = lane & 7;
        qq[i] = q << 3;
        goA[i] = (size_t)(brow+r)*1024 + ((c^(r&7))<<3);
        goB[i] = (size_t)(bcol+r)*1024 + ((c^(r&7))<<3);
    }
    f4v acc[2][2] = {};
    {
        u16* L = lds[0];
        #pragma unroll
        for (int i = 0; i < 2; ++i){
            gl16(Ah + goA[i], L + qq[i]);
            gl16(Bh + goB[i], L + 4096 + qq[i]);
        }
    }
    int cur = 0;
    for (int kt = 0; kt < 16; ++kt){
        __syncthreads();
        if (kt < 15){
            u16* L = lds[cur^1];
            const int k0 = (kt+1) << 6;
            #pragma unroll
            for (int i = 0; i < 2; ++i){
                gl16(Ah + goA[i] + k0, L + qq[i]);
                gl16(Bh + goB[i] + k0, L + 4096 + qq[i]);
            }
        }
        const u16* L = lds[cur];
        #pragma unroll
        for (int ks = 0; ks < 2; ++ks){
            const int ch = (ks << 2) + g;
            s8v a_h[2], b_h[2];
            #pragma unroll
            for (int f = 0; f < 2; ++f){
                const int ra = wm+(f<<4)+lr, rb = wn+(f<<4)+lr;
                a_h[f] = *(const s8v*)&L[sidx(ra,ch)];
                b_h[f] = *(const s8v*)&L[4096 + sidx(rb,ch)];
            }
            __builtin_amdgcn_s_setprio(1);
            #pragma unroll
            for (int mf = 0; mf < 2; ++mf)
                #pragma unroll
                for (int nf = 0; nf < 2; ++nf)
                    acc[mf][nf] = __builtin_amdgcn_mfma_f32_16x16x32_bf16(a_h[mf], b_h[nf], acc[mf][nf], 0,0,0);
            __builtin_amdgcn_s_setprio(0);
        }
        cur ^= 1;
    }
    const int orr = g << 2;
    #pragma unroll
    for (int mf = 0; mf < 2; ++mf)
        #pragma unroll
        for (int nf = 0; nf < 2; ++nf)
            #pragma unroll
            for (int r = 0; r < 4; ++r){
                const int orow = brow + wm + (mf<<4) + orr + r;
                const int ocol = bcol + wn + (nf<<4) + lr;
                const size_t off = (size_t)orow*1024 + ocol;
                const float av = acc[mf][nf][r];
                if (MODE == 0 || MODE == 1){
                    u16 h,l; splitf(av, h, l);
                    Ch[off] = h; Cl[off] = l;
                }
                if (MODE == 1){
                    float a  = pairf(Bh, Bl, off);      // A
                    float a2 = pairf(Ah, Al, off);      // -A^2
                    float mb = (1.0f/24.0f)*a - (1.0f/120.0f)*a2 + (1.0f/720.0f)*av
                             + (orow == ocol ? (1.0f/6.0f) : 0.0f);
                    u16 h,l; splitf(mb, h, l);
                    O2h[off] = h; O2l[off] = l;
                }
                if (MODE == 2){
                    float a  = pairf(Pah, Pal, off);    // A
                    float a2 = pairf(P2h, P2l, off);    // -A^2
                    float e = a - 0.5f*a2 - av + (orow == ocol ? 1.0f : 0.0f);
                    u16 h,l; splitf(e, h, l);
                    O2h[off] = h; O2l[off] = l;
                    if (z == 2){                        // also write E2^T
                        const size_t offT = (size_t)ocol*1024 + orow;
                        E2t[offT] = h; E2t[S + offT] = l;
                    }
                }
            }
}

// C = A * Bt^T, 32x32 tile, 4 waves (1 frag each), 3-pass split (composition needs diag accuracy),
// DMA staging, dbuf.
__global__ __launch_bounds__(256) void gemm32_k(const u16* __restrict__ Ah, const u16* __restrict__ Bh,
                                                u16* __restrict__ Ch){
    __shared__ u16 lds[2][8192];   // per buf: Ah 0, Al 2048, Bh 4096, Bl 6144 (32x64 u16 each)
    const u16* Al = Ah + S; const u16* Bl = Bh + S;
    u16* Cl = Ch + S;
    const int t = threadIdx.x;
    const int brow = blockIdx.y << 5, bcol = blockIdx.x << 5;
    const int lane = t & 63, w = t >> 6;
    const int wm = (w >> 1) << 4, wn = (w & 1) << 4;
    const int lr = lane & 15, g = lane >> 4;
    const u16* gsrc = (w == 0) ? Ah : (w == 1) ? Al : (w == 2) ? Bh : Bl;
    const int rbase = (w < 2) ? brow : bcol;
    const int lreg = w << 11;
    int qq[4]; size_t go[4];
    #pragma unroll
    for (int i = 0; i < 4; ++i){
        int q = (i<<6) + lane;
        int r = q >> 3, c = lane & 7;
        qq[i] = lreg + (q << 3);
        go[i] = (size_t)(rbase+r)*1024 + ((c^(r&7))<<3);
    }
    f4v acc = {};
    {
        u16* L = lds[0];
        #pragma unroll
        for (int i = 0; i < 4; ++i) gl16(gsrc + go[i], L + qq[i]);
    }
    int cur = 0;
    for (int kt = 0; kt < 16; ++kt){
        __syncthreads();
        if (kt < 15){
            u16* L = lds[cur^1];
            const int k0 = (kt+1) << 6;
            #pragma unroll
            for (int i = 0; i < 4; ++i) gl16(gsrc + go[i] + k0, L + qq[i]);
        }
        const u16* L = lds[cur];
        #pragma unroll
        for (int ks = 0; ks < 2; ++ks){
            const int ch = (ks << 2) + g;
            const int ra = wm + lr, rb = wn + lr;
            s8v a_h = *(const s8v*)&L[sidx(ra,ch)];
            s8v a_l = *(const s8v*)&L[2048 + sidx(ra,ch)];
            s8v b_h = *(const s8v*)&L[4096 + sidx(rb,ch)];
            s8v b_l = *(const s8v*)&L[6144 + sidx(rb,ch)];
            acc = __builtin_amdgcn_mfma_f32_16x16x32_bf16(a_h, b_h, acc, 0,0,0);
            acc = __builtin_amdgcn_mfma_f32_16x16x32_bf16(a_l, b_h, acc, 0,0,0);
            acc = __builtin_amdgcn_mfma_f32_16x16x32_bf16(a_h, b_l, acc, 0,0,0);
        }
        cur ^= 1;
    }
    const int orr = g << 2;
    #pragma unroll
    for (int r = 0; r < 4; ++r){
        const int orow = brow + wm + orr + r;
        const int ocol = bcol + wn + lr;
        const size_t off = (size_t)orow*1024 + ocol;
        u16 h,l; splitf(acc[r], h, l);
        Ch[off] = h; Cl[off] = l;
    }
}

// Y[16384,1024] = Xh * Rh.  128x128 tile, BK=64, 8 waves (wave tile 64x32), single pass,
// DMA staging of Xh + Rth hi planes only, dbuf (64KB -> 2 blocks/CU), 1 barrier/K-step.
__global__ __launch_bounds__(512) void gemm_big2(const u16* __restrict__ Xh, const u16* __restrict__ Rth,
                                                 float* __restrict__ Y){
    __shared__ u16 lds[2][16384];  // per buf: X 0..8191 (128x64), Bh 8192..16383 (128x64)
    const int bid = blockIdx.x;
    const int swz = (bid & 7)*128 + (bid >> 3);    // chunked XCD swizzle (1024 blocks, bijective)
    const int by = swz >> 3, bx = swz & 7;
    const int brow = by << 7, bcol = bx << 7;
    const int t = threadIdx.x;
    const int lane = t & 63, w = t >> 6;
    const int wm = (w >> 2) << 6, wn = (w & 3) << 5;   // 2x4 wave grid, wave tile 64x32
    const int lr = lane & 15, g = lane >> 4;
    int xq[2]; size_t gx[2], gb[2];
    #pragma unroll
    for (int i = 0; i < 2; ++i){
        int q = (((w<<1)+i)<<6) + lane;   // 0..1023 chunks per plane
        int r = q >> 3, c = lane & 7;
        xq[i] = q << 3;
        gx[i] = (size_t)(brow+r)*1024 + ((c^(r&7))<<3);
        gb[i] = (size_t)(bcol+r)*1024 + ((c^(r&7))<<3);
    }
    f4v acc[4][2] = {};
    {
        u16* L = lds[0];
        #pragma unroll
        for (int i = 0; i < 2; ++i){
            gl16(Xh  + gx[i], L + xq[i]);
            gl16(Rth + gb[i], L + 8192 + xq[i]);
        }
    }
    int cur = 0;
    for (int kt = 0; kt < 16; ++kt){
        __syncthreads();
        if (kt < 15){
            u16* L = lds[cur^1];
            const int k0 = (kt+1) << 6;
            #pragma unroll
            for (int i = 0; i < 2; ++i){
                gl16(Xh  + gx[i] + k0, L + xq[i]);
                gl16(Rth + gb[i] + k0, L + 8192 + xq[i]);
            }
        }
        const u16* L = lds[cur];
        #pragma unroll
        for (int ks = 0; ks < 2; ++ks){
            const int ch = (ks << 2) + g;
            s8v bh[2];
            #pragma unroll
            for (int nf = 0; nf < 2; ++nf){
                const int rb = wn+(nf<<4)+lr;
                bh[nf] = *(const s8v*)&L[8192 + sidx(rb,ch)];
            }
            __builtin_amdgcn_s_setprio(1);
            #pragma unroll
            for (int mf = 0; mf < 4; ++mf){
                const int ra = wm+(mf<<4)+lr;
                s8v a = *(const s8v*)&L[sidx(ra,ch)];
                #pragma unroll
                for (int nf = 0; nf < 2; ++nf)
                    acc[mf][nf] = __builtin_amdgcn_mfma_f32_16x16x32_bf16(a, bh[nf], acc[mf][nf], 0,0,0);
            }
            __builtin_amdgcn_s_setprio(0);
        }
        cur ^= 1;
    }
    const int orr = g << 2;
    #pragma unroll
    for (int mf = 0; mf < 4; ++mf)
        #pragma unroll
        for (int nf = 0; nf < 2; ++nf)
            #pragma unroll
            for (int r = 0; r < 4; ++r){
                int orow = brow + wm + (mf<<4) + orr + r;
                int ocol = bcol + wn + (nf<<4) + lr;
                Y[(size_t)orow*1024 + ocol] = acc[mf][nf][r];
            }
}

// Fallback (no workspace): reg-staged 128x128, X converted on the fly, 2-pass (Xh*Bh + Xh*Bl).
__global__ __launch_bounds__(256) void gemm_big_f(const float* __restrict__ Xv, const u16* __restrict__ Rth,
                                                  float* __restrict__ Y){
    __shared__ u16 Xs[128*64], Bhs[128*64], Bls[128*64];
    const u16* Rtl = Rth + S;
    const int bid = blockIdx.x;
    const int swz = (bid & 7)*128 + (bid >> 3);
    const int bx = swz & 7, by = swz >> 3;
    const int brow = by << 7, bcol = bx << 7;
    const int t = threadIdx.x;
    const int sr = t >> 1, cb = (t & 1) << 2;
    const int lane = t & 63, w = t >> 6;
    const int wm = (w >> 1) << 6, wn = (w & 1) << 6;
    const int lr = lane & 15, g = lane >> 4;
    s8v xr[4], bhr[4], blr[4];
    auto load_tile = [&](int k0){
        #pragma unroll
        for (int i = 0; i < 4; ++i){
            const size_t bo = (size_t)(bcol+sr)*1024 + k0 + ((cb+i)<<3);
            bhr[i] = *(const s8v*)(Rth + bo);
            blr[i] = *(const s8v*)(Rtl + bo);
        }
        #pragma unroll
        for (int i = 0; i < 4; ++i){
            const float* p = Xv + (size_t)(brow+sr)*1024 + k0 + ((cb+i)<<3);
            float4 f0 = *(const float4*)(p), f1 = *(const float4*)(p+4);
            float xs[8] = {f0.x,f0.y,f0.z,f0.w,f1.x,f1.y,f1.z,f1.w};
            #pragma unroll
            for (int j = 0; j < 8; ++j) xr[i][j] = (short)f2bf(xs[j]);
        }
    };
    load_tile(0);
    f4v acc[4][4] = {};
    for (int k0 = 0; k0 < 1024; k0 += 64){
        __syncthreads();
        #pragma unroll
        for (int i = 0; i < 4; ++i){
            const int si = sidx(sr, cb+i);
            *(s8v*)&Xs[si]  = xr[i];
            *(s8v*)&Bhs[si] = bhr[i];
            *(s8v*)&Bls[si] = blr[i];
        }
        __syncthreads();
        if (k0 < 960) load_tile(k0 + 64);
        #pragma unroll
        for (int ks = 0; ks < 2; ++ks){
            const int ch = (ks << 2) + g;
            s8v bhf[4], blf[4];
            #pragma unroll
            for (int nf = 0; nf < 4; ++nf){
                bhf[nf] = *(const s8v*)&Bhs[sidx(wn+(nf<<4)+lr, ch)];
                blf[nf] = *(const s8v*)&Bls[sidx(wn+(nf<<4)+lr, ch)];
            }
            #pragma unroll
            for (int mf = 0; mf < 4; ++mf){
                s8v ah = *(const s8v*)&Xs[sidx(wm+(mf<<4)+lr, ch)];
                #pragma unroll
                for (int nf = 0; nf < 4; ++nf){
                    acc[mf][nf] = __builtin_amdgcn_mfma_f32_16x16x32_bf16(ah, bhf[nf], acc[mf][nf], 0,0,0);
                    acc[mf][nf] = __builtin_amdgcn_mfma_f32_16x16x32_bf16(ah, blf[nf], acc[mf][nf], 0,0,0);
                }
            }
        }
    }
    const int orr = g << 2;
    #pragma unroll
    for (int mf = 0; mf < 4; ++mf)
        #pragma unroll
        for (int nf = 0; nf < 4; ++nf)
            #pragma unroll
            for (int r = 0; r < 4; ++r){
                int orow = brow + wm + (mf<<4) + orr + r;
                int ocol = bcol + wn + (nf<<4) + lr;
                Y[(size_t)orow*1024 + ocol] = acc[mf][nf][r];
            }
}

extern "C" void kernel_launch(void* const* d_in, const int* in_sizes, int n_in,
                              void* d_out, int out_size, void* d_ws, size_t ws_size,
                              hipStream_t stream) {
    const float* X = (const float*)d_in[0];   // [16384,1024] fp32
    const float* G = (const float*)d_in[1];   // [3,1024,1024] fp32
    float* out = (float*)d_out;
    u16* ob = (u16*)d_out;                    // 16 pair-slots of 2*S u16 each
    auto slot = [&](int i){ return ob + (size_t)i*2*S; };
    u16* RT = (u16*)d_ws;                     // R^T split pair (4 MB)
    u16* Xh = RT + (size_t)2*S;               // X hi bf16 (32 MB)
    const bool ws_ok = ws_size >= (size_t)36*S; // bytes: 2S*2 (RT) + 16S*2 (Xh)

    dim3 b(256);
    // slots: A:0-2  A2':3-5  A3:6-8  Mb:9-11  E:12-14  E2t:15  M1:0
    pre_k<<<dim3(768), b, 0, stream>>>(G, slot(0));                                   // A pair
    if (ws_ok)
        gemm64_k<0,true><<<dim3(48,16,3), b, 0, stream>>>(slot(0), slot(0), slot(3),
                                                          slot(0), slot(0), slot(3), slot(15),
                                                          X, Xh);                     // A2' = -A^2 (+X conv)
    else
        gemm64_k<0,false><<<dim3(16,16,3), b, 0, stream>>>(slot(0), slot(0), slot(3),
                                                           slot(0), slot(0), slot(3), slot(15),
                                                           X, Xh);
    gemm64_k<1,false><<<dim3(16,16,3), b, 0, stream>>>(slot(3), slot(0), slot(6),
                                                       slot(0), slot(3), slot(9), slot(15),
                                                       X, Xh);                        // A3 ; Mb
    gemm64_k<2,false><<<dim3(16,16,3), b, 0, stream>>>(slot(9), slot(6), slot(9),
                                                       slot(0), slot(3), slot(12), slot(15),
                                                       X, Xh);                        // E (+E2^T for z=2)
    gemm32_k<<<dim3(32,32), b, 0, stream>>>(slot(15), slot(13), slot(0));             // M1 = E2^T*E1^T
    gemm32_k<<<dim3(32,32), b, 0, stream>>>(slot(0), slot(12), RT);                   // RT = M1*E0^T
    if (ws_ok)
        gemm_big2<<<dim3(1024), dim3(512), 0, stream>>>(Xh, RT, out);
    else
        gemm_big_f<<<dim3(1024), b, 0, stream>>>(X, RT, out);
}

// Round 8
// 140.170 us; speedup vs baseline: 1.5894x; 1.0512x over previous
//
#include <hip/hip_runtime.h>

#define S 1048576
typedef unsigned short u16;
typedef unsigned int u32;
typedef __attribute__((ext_vector_type(8))) short s8v;   // 8 bf16 (4 VGPRs)
typedef __attribute__((ext_vector_type(4))) float f4v;   // MFMA acc

__device__ __forceinline__ float bf2f(u16 u){
    union { float f; u32 u; } v; v.u = ((u32)u) << 16; return v.f;
}
__device__ __forceinline__ u16 f2bf(float x){
    u32 u = __float_as_uint(x);
    u32 r = (u + 0x7FFFu + ((u >> 16) & 1u)) >> 16;   // RNE
    return (u16)r;
}
__device__ __forceinline__ void splitf(float x, u16& h, u16& l){
    h = f2bf(x);
    l = f2bf(x - bf2f(h));
}
__device__ __forceinline__ float pairf(const u16* H, const u16* L, size_t off){
    return bf2f(H[off]) + bf2f(L[off]);
}
// XOR-swizzled LDS index (u16 units): 128-byte rows of 8 16B chunks, chunk ^= row&7
__device__ __forceinline__ int sidx(int r, int c){ return (r<<6) + (((c) ^ (r&7))<<3); }
// async global->LDS, 16B per lane; LDS dest = wave-uniform base + lane*16
__device__ __forceinline__ void gl16(const void* g, void* l){
    __builtin_amdgcn_global_load_lds((const __attribute__((address_space(1))) void*)g,
                                     (__attribute__((address_space(3))) void*)l, 16, 0, 0);
}

// A_z = 0.5*(G_z - G_z^T) split pair (64x64 tiles, z=bid>>8). 768 blocks.
__global__ __launch_bounds__(256) void pre_k(const float* __restrict__ G, u16* __restrict__ Abase){
    __shared__ float Gt[64][65];
    const int bid = blockIdx.x;
    const int t = threadIdx.x;
    const int bx = bid & 15, by = (bid >> 4) & 15, z = bid >> 8;
    const float* Gz = G + (size_t)z*S;
    u16* Ah = Abase + (size_t)z*2*S;
    u16* Al = Ah + S;
    const int row = t >> 2, cq = (t & 3) << 4;
    const int r0 = by << 6, c0 = bx << 6;
    #pragma unroll
    for (int g = 0; g < 4; ++g){
        float4 v = *(const float4*)(Gz + (size_t)(c0+row)*1024 + r0 + cq + g*4);
        Gt[row][cq+g*4+0]=v.x; Gt[row][cq+g*4+1]=v.y; Gt[row][cq+g*4+2]=v.z; Gt[row][cq+g*4+3]=v.w;
    }
    __syncthreads();
    #pragma unroll
    for (int g = 0; g < 2; ++g){
        const float* p = Gz + (size_t)(r0+row)*1024 + c0 + cq + g*8;
        float4 v0 = *(const float4*)(p);
        float4 v1 = *(const float4*)(p+4);
        float xs[8] = {v0.x,v0.y,v0.z,v0.w,v1.x,v1.y,v1.z,v1.w};
        s8v sh, sl;
        #pragma unroll
        for (int i = 0; i < 8; ++i){
            float gt = Gt[cq + g*8 + i][row];
            u16 h,l; splitf(0.5f*(xs[i]-gt), h, l);
            sh[i] = (short)h; sl[i] = (short)l;
        }
        *(s8v*)(Ah + (size_t)(r0+row)*1024 + c0 + cq + g*8) = sh;
        *(s8v*)(Al + (size_t)(r0+row)*1024 + c0 + cq + g*8) = sl;
    }
}

// acc = Ah * Bth^T, single-pass bf16 MFMA (hi planes only), DMA staging, dbuf, 1 barrier/K-step.
// Skew identities: A*A^T = -A^2 ; (-A^2)*A^T = A^3.
// MODE 0: C pair = acc.
// MODE 1: C pair = acc AND O2 = (1/6)I + (1/24)*Bt - (1/120)*Aop + (1/720)*acc   (O2 = Mb)
// MODE 2: O2 only = I + Pa - 0.5*Pa2 - acc  (O2 = E); z==2 also writes E2^T pair to E2t.
// XFUSE: blocks with blockIdx.x >= 16 convert X fp32 -> bf16 hi (grid-stride).
template<int MODE, bool XFUSE>
__global__ __launch_bounds__(256) void gemm64_k(const u16* __restrict__ Abase, const u16* __restrict__ Btbase,
                                                u16* __restrict__ Cbase,
                                                const u16* __restrict__ Pab, const u16* __restrict__ Pa2b,
                                                u16* __restrict__ O2base, u16* __restrict__ E2t,
                                                const float* __restrict__ X, u16* __restrict__ Xh){
    __shared__ u16 lds[2][8192];   // per buf: Ah 0..4095, Bh 4096..8191 (64x64 u16 each)
    const int t = threadIdx.x;
    if (XFUSE && blockIdx.x >= 16){
        const int e = ((int)(blockIdx.z*gridDim.y + blockIdx.y))*((int)gridDim.x - 16) + ((int)blockIdx.x - 16);
        const int E = (int)(gridDim.x - 16)*(int)gridDim.y*(int)gridDim.z;
        for (int u = e; u < 8192; u += E){
            const size_t idx8 = (size_t)u*2048 + (size_t)t*8;
            float4 v0 = *(const float4*)(X+idx8);
            float4 v1 = *(const float4*)(X+idx8+4);
            float xs[8] = {v0.x,v0.y,v0.z,v0.w,v1.x,v1.y,v1.z,v1.w};
            s8v h;
            #pragma unroll
            for (int i = 0; i < 8; ++i) h[i] = (short)f2bf(xs[i]);
            *(s8v*)(Xh+idx8) = h;
        }
        return;
    }
    const int z = blockIdx.z;
    const u16* Ah = Abase  + (size_t)z*2*S; const u16* Al = Ah + S;
    const u16* Bh = Btbase + (size_t)z*2*S; const u16* Bl = Bh + S;
    u16* Ch = Cbase + (size_t)z*2*S;        u16* Cl = Ch + S;
    const u16* Pah = Pab + (size_t)z*2*S;   const u16* Pal = Pah + S;
    const u16* P2h = Pa2b + (size_t)z*2*S;  const u16* P2l = P2h + S;
    u16* O2h = O2base + (size_t)z*2*S;      u16* O2l = O2h + S;
    const int brow = blockIdx.y << 6, bcol = blockIdx.x << 6;
    const int lane = t & 63, w = t >> 6;
    const int wm = (w >> 1) << 5, wn = (w & 1) << 5;
    const int lr = lane & 15, g = lane >> 4;
    int qq[2]; size_t goA[2], goB[2];
    #pragma unroll
    for (int i = 0; i < 2; ++i){
        int q = (((w<<1)+i)<<6) + lane;
        int r = q >> 3, c = lane & 7;
        qq[i] = q << 3;
        goA[i] = (size_t)(brow+r)*1024 + ((c^(r&7))<<3);
        goB[i] = (size_t)(bcol+r)*1024 + ((c^(r&7))<<3);
    }
    f4v acc[2][2] = {};
    {
        u16* L = lds[0];
        #pragma unroll
        for (int i = 0; i < 2; ++i){
            gl16(Ah + goA[i], L + qq[i]);
            gl16(Bh + goB[i], L + 4096 + qq[i]);
        }
    }
    int cur = 0;
    for (int kt = 0; kt < 16; ++kt){
        __syncthreads();
        if (kt < 15){
            u16* L = lds[cur^1];
            const int k0 = (kt+1) << 6;
            #pragma unroll
            for (int i = 0; i < 2; ++i){
                gl16(Ah + goA[i] + k0, L + qq[i]);
                gl16(Bh + goB[i] + k0, L + 4096 + qq[i]);
            }
        }
        const u16* L = lds[cur];
        #pragma unroll
        for (int ks = 0; ks < 2; ++ks){
            const int ch = (ks << 2) + g;
            s8v a_h[2], b_h[2];
            #pragma unroll
            for (int f = 0; f < 2; ++f){
                const int ra = wm+(f<<4)+lr, rb = wn+(f<<4)+lr;
                a_h[f] = *(const s8v*)&L[sidx(ra,ch)];
                b_h[f] = *(const s8v*)&L[4096 + sidx(rb,ch)];
            }
            __builtin_amdgcn_s_setprio(1);
            #pragma unroll
            for (int mf = 0; mf < 2; ++mf)
                #pragma unroll
                for (int nf = 0; nf < 2; ++nf)
                    acc[mf][nf] = __builtin_amdgcn_mfma_f32_16x16x32_bf16(a_h[mf], b_h[nf], acc[mf][nf], 0,0,0);
            __builtin_amdgcn_s_setprio(0);
        }
        cur ^= 1;
    }
    const int orr = g << 2;
    #pragma unroll
    for (int mf = 0; mf < 2; ++mf)
        #pragma unroll
        for (int nf = 0; nf < 2; ++nf)
            #pragma unroll
            for (int r = 0; r < 4; ++r){
                const int orow = brow + wm + (mf<<4) + orr + r;
                const int ocol = bcol + wn + (nf<<4) + lr;
                const size_t off = (size_t)orow*1024 + ocol;
                const float av = acc[mf][nf][r];
                if (MODE == 0 || MODE == 1){
                    u16 h,l; splitf(av, h, l);
                    Ch[off] = h; Cl[off] = l;
                }
                if (MODE == 1){
                    float a  = pairf(Bh, Bl, off);      // A
                    float a2 = pairf(Ah, Al, off);      // -A^2
                    float mb = (1.0f/24.0f)*a - (1.0f/120.0f)*a2 + (1.0f/720.0f)*av
                             + (orow == ocol ? (1.0f/6.0f) : 0.0f);
                    u16 h,l; splitf(mb, h, l);
                    O2h[off] = h; O2l[off] = l;
                }
                if (MODE == 2){
                    float a  = pairf(Pah, Pal, off);    // A
                    float a2 = pairf(P2h, P2l, off);    // -A^2
                    float e = a - 0.5f*a2 - av + (orow == ocol ? 1.0f : 0.0f);
                    u16 h,l; splitf(e, h, l);
                    O2h[off] = h; O2l[off] = l;
                    if (z == 2){                        // also write E2^T
                        const size_t offT = (size_t)ocol*1024 + orow;
                        E2t[offT] = h; E2t[S + offT] = l;
                    }
                }
            }
}

// Y[16384,1024] = Xh * Rh.  256x256 tile, BK=64, 8 waves (wave tile 128x64: 8x4 frags),
// single-pass hi, DMA staging, dbuf (128KB), 1 barrier/K-step, bijective XCD swizzle.
// Per K=32 sub-step: 12 ds_read_b128 (144cy) vs 32 MFMA (155cy) -> MFMA-bound geometry.
__global__ __launch_bounds__(512) void gemm_big3(const u16* __restrict__ Xh, const u16* __restrict__ Rth,
                                                 float* __restrict__ Y){
    __shared__ u16 lds[2][32768];  // per buf: X 0..16383 (256x64), B 16384..32767 (256x64)
    const int bid = blockIdx.x;
    const int swz = (bid & 7)*32 + (bid >> 3);     // 256 blocks, 8 XCDs, bijective
    const int by = swz >> 2, bx = swz & 3;
    const int brow = by << 8, bcol = bx << 8;
    const int t = threadIdx.x;
    const int lane = t & 63, w = t >> 6;
    const int wm = (w >> 2) << 7, wn = (w & 3) << 6;   // 2x4 wave grid, wave tile 128x64
    const int lr = lane & 15, g = lane >> 4;
    int xq[4]; size_t gx[4], gb[4];
    #pragma unroll
    for (int i = 0; i < 4; ++i){
        int q = (((w<<2)+i)<<6) + lane;   // 0..2047 chunks per region
        int r = q >> 3, c = lane & 7;
        xq[i] = q << 3;
        gx[i] = (size_t)(brow+r)*1024 + ((c^(r&7))<<3);
        gb[i] = (size_t)(bcol+r)*1024 + ((c^(r&7))<<3);
    }
    f4v acc[8][4] = {};
    {
        u16* L = lds[0];
        #pragma unroll
        for (int i = 0; i < 4; ++i){
            gl16(Xh  + gx[i], L + xq[i]);
            gl16(Rth + gb[i], L + 16384 + xq[i]);
        }
    }
    int cur = 0;
    for (int kt = 0; kt < 16; ++kt){
        __syncthreads();
        if (kt < 15){
            u16* L = lds[cur^1];
            const int k0 = (kt+1) << 6;
            #pragma unroll
            for (int i = 0; i < 4; ++i){
                gl16(Xh  + gx[i] + k0, L + xq[i]);
                gl16(Rth + gb[i] + k0, L + 16384 + xq[i]);
            }
        }
        const u16* L = lds[cur];
        #pragma unroll
        for (int ks = 0; ks < 2; ++ks){
            const int ch = (ks << 2) + g;
            s8v bh[4];
            #pragma unroll
            for (int nf = 0; nf < 4; ++nf){
                const int rb = wn+(nf<<4)+lr;
                bh[nf] = *(const s8v*)&L[16384 + sidx(rb,ch)];
            }
            __builtin_amdgcn_s_setprio(1);
            #pragma unroll
            for (int mf = 0; mf < 8; ++mf){
                const int ra = wm+(mf<<4)+lr;
                s8v a = *(const s8v*)&L[sidx(ra,ch)];
                #pragma unroll
                for (int nf = 0; nf < 4; ++nf)
                    acc[mf][nf] = __builtin_amdgcn_mfma_f32_16x16x32_bf16(a, bh[nf], acc[mf][nf], 0,0,0);
            }
            __builtin_amdgcn_s_setprio(0);
        }
        cur ^= 1;
    }
    const int orr = g << 2;
    #pragma unroll
    for (int mf = 0; mf < 8; ++mf)
        #pragma unroll
        for (int nf = 0; nf < 4; ++nf)
            #pragma unroll
            for (int r = 0; r < 4; ++r){
                int orow = brow + wm + (mf<<4) + orr + r;
                int ocol = bcol + wn + (nf<<4) + lr;
                Y[(size_t)orow*1024 + ocol] = acc[mf][nf][r];
            }
}

// Fallback (no workspace): reg-staged 128x128, X converted on the fly, 2-pass (Xh*Bh + Xh*Bl).
__global__ __launch_bounds__(256) void gemm_big_f(const float* __restrict__ Xv, const u16* __restrict__ Rth,
                                                  float* __restrict__ Y){
    __shared__ u16 Xs[128*64], Bhs[128*64], Bls[128*64];
    const u16* Rtl = Rth + S;
    const int bid = blockIdx.x;
    const int swz = (bid & 7)*128 + (bid >> 3);
    const int bx = swz & 7, by = swz >> 3;
    const int brow = by << 7, bcol = bx << 7;
    const int t = threadIdx.x;
    const int sr = t >> 1, cb = (t & 1) << 2;
    const int lane = t & 63, w = t >> 6;
    const int wm = (w >> 1) << 6, wn = (w & 1) << 6;
    const int lr = lane & 15, g = lane >> 4;
    s8v xr[4], bhr[4], blr[4];
    auto load_tile = [&](int k0){
        #pragma unroll
        for (int i = 0; i < 4; ++i){
            const size_t bo = (size_t)(bcol+sr)*1024 + k0 + ((cb+i)<<3);
            bhr[i] = *(const s8v*)(Rth + bo);
            blr[i] = *(const s8v*)(Rtl + bo);
        }
        #pragma unroll
        for (int i = 0; i < 4; ++i){
            const float* p = Xv + (size_t)(brow+sr)*1024 + k0 + ((cb+i)<<3);
            float4 f0 = *(const float4*)(p), f1 = *(const float4*)(p+4);
            float xs[8] = {f0.x,f0.y,f0.z,f0.w,f1.x,f1.y,f1.z,f1.w};
            #pragma unroll
            for (int j = 0; j < 8; ++j) xr[i][j] = (short)f2bf(xs[j]);
        }
    };
    load_tile(0);
    f4v acc[4][4] = {};
    for (int k0 = 0; k0 < 1024; k0 += 64){
        __syncthreads();
        #pragma unroll
        for (int i = 0; i < 4; ++i){
            const int si = sidx(sr, cb+i);
            *(s8v*)&Xs[si]  = xr[i];
            *(s8v*)&Bhs[si] = bhr[i];
            *(s8v*)&Bls[si] = blr[i];
        }
        __syncthreads();
        if (k0 < 960) load_tile(k0 + 64);
        #pragma unroll
        for (int ks = 0; ks < 2; ++ks){
            const int ch = (ks << 2) + g;
            s8v bhf[4], blf[4];
            #pragma unroll
            for (int nf = 0; nf < 4; ++nf){
                bhf[nf] = *(const s8v*)&Bhs[sidx(wn+(nf<<4)+lr, ch)];
                blf[nf] = *(const s8v*)&Bls[sidx(wn+(nf<<4)+lr, ch)];
            }
            #pragma unroll
            for (int mf = 0; mf < 4; ++mf){
                s8v ah = *(const s8v*)&Xs[sidx(wm+(mf<<4)+lr, ch)];
                #pragma unroll
                for (int nf = 0; nf < 4; ++nf){
                    acc[mf][nf] = __builtin_amdgcn_mfma_f32_16x16x32_bf16(ah, bhf[nf], acc[mf][nf], 0,0,0);
                    acc[mf][nf] = __builtin_amdgcn_mfma_f32_16x16x32_bf16(ah, blf[nf], acc[mf][nf], 0,0,0);
                }
            }
        }
    }
    const int orr = g << 2;
    #pragma unroll
    for (int mf = 0; mf < 4; ++mf)
        #pragma unroll
        for (int nf = 0; nf < 4; ++nf)
            #pragma unroll
            for (int r = 0; r < 4; ++r){
                int orow = brow + wm + (mf<<4) + orr + r;
                int ocol = bcol + wn + (nf<<4) + lr;
                Y[(size_t)orow*1024 + ocol] = acc[mf][nf][r];
            }
}

extern "C" void kernel_launch(void* const* d_in, const int* in_sizes, int n_in,
                              void* d_out, int out_size, void* d_ws, size_t ws_size,
                              hipStream_t stream) {
    const float* X = (const float*)d_in[0];   // [16384,1024] fp32
    const float* G = (const float*)d_in[1];   // [3,1024,1024] fp32
    float* out = (float*)d_out;
    u16* ob = (u16*)d_out;                    // 16 pair-slots of 2*S u16 each
    auto slot = [&](int i){ return ob + (size_t)i*2*S; };
    u16* RT = (u16*)d_ws;                     // R^T split pair (4 MB)
    u16* Xh = RT + (size_t)2*S;               // X hi bf16 (32 MB)
    const bool ws_ok = ws_size >= (size_t)36*S; // bytes: 2S*2 (RT) + 16S*2 (Xh)

    dim3 b(256);
    // slots: A:0-2  A2':3-5  A3:6-8  Mb:9-11  E:12-14  E2t:15  M1:0
    pre_k<<<dim3(768), b, 0, stream>>>(G, slot(0));                                   // A pair
    if (ws_ok)
        gemm64_k<0,true><<<dim3(48,16,3), b, 0, stream>>>(slot(0), slot(0), slot(3),
                                                          slot(0), slot(0), slot(3), slot(15),
                                                          X, Xh);                     // A2' = -A^2 (+X conv)
    else
        gemm64_k<0,false><<<dim3(16,16,3), b, 0, stream>>>(slot(0), slot(0), slot(3),
                                                           slot(0), slot(0), slot(3), slot(15),
                                                           X, Xh);
    gemm64_k<1,false><<<dim3(16,16,3), b, 0, stream>>>(slot(3), slot(0), slot(6),
                                                       slot(0), slot(3), slot(9), slot(15),
                                                       X, Xh);                        // A3 ; Mb
    gemm64_k<2,false><<<dim3(16,16,3), b, 0, stream>>>(slot(9), slot(6), slot(9),
                                                       slot(0), slot(3), slot(12), slot(15),
                                                       X, Xh);                        // E (+E2^T for z=2)
    gemm64_k<0,false><<<dim3(16,16,1), b, 0, stream>>>(slot(15), slot(13), slot(0),
                                                       slot(0), slot(0), slot(0), slot(15),
                                                       X, Xh);                        // M1 = E2^T*E1^T (1-pass)
    gemm64_k<0,false><<<dim3(16,16,1), b, 0, stream>>>(slot(0), slot(12), RT,
                                                       slot(0), slot(0), RT, slot(15),
                                                       X, Xh);                        // RT = M1*E0^T (1-pass)
    if (ws_ok)
        gemm_big3<<<dim3(256), dim3(512), 0, stream>>>(Xh, RT, out);
    else
        gemm_big_f<<<dim3(1024), b, 0, stream>>>(X, RT, out);
}